// Round 14
// baseline (36.033 us; speedup 1.0000x reference)
//
#include <hip/hip_runtime.h>
#include <math.h>

#define N_ROWS 1024
#define RANK   8
#define M_COLS 4096

#define R_ROWS   2      // n-rows per thread
#define T_PTS    2      // direct points per thread in [1,2048], stride 1024
#define M_STRIDE 1024

// Static device scratch (fully overwritten every call before read).
__device__ float2 g_Hft[RANK * M_COLS];    // full FFT of softplus(H), 256 KB
__device__ float4 g_Tab4[N_ROWS * RANK];   // {vr, vi, wcr, wci} per (n,d), 128 KB
__device__ float2 g_Tab2[N_ROWS * RANK];   // {ws, tau}          per (n,d),  64 KB

// fast softplus: 2 trans + ~4 VALU. exact for x>20; inputs are ~N(0,1).
__device__ __forceinline__ float softplus_f(float x) {
    float t = __expf(x);
    float r = 0.69314718056f * __log2f(1.0f + t);
    return (x > 20.0f) ? x : r;
}
// hw trig: v_sin/v_cos compute sin/cos(2*pi*x), x in revolutions.
__device__ __forceinline__ float sin_rev(float x) { return __builtin_amdgcn_sinf(x); }
__device__ __forceinline__ float cos_rev(float x) { return __builtin_amdgcn_cosf(x); }
__device__ __forceinline__ float fract_f(float x) { return __builtin_amdgcn_fractf(x); }
// block-uniform float -> SGPR
__device__ __forceinline__ float rfl(float x) {
    return __int_as_float(__builtin_amdgcn_readfirstlane(__float_as_int(x)));
}

// ---------------------------------------------------------------------------
// Fused FFT: softplus(H) + 64x64 Cooley-Tukey DFT -> g_Hft. Side-job (blocks
// 0..31): per-(n,d) trig table. (UNCHANGED from R13)
// ---------------------------------------------------------------------------
__global__ void fft_fused(const float* __restrict__ H,
                          const float* __restrict__ W,
                          const float* __restrict__ tau) {
    __shared__ float  sHs[M_COLS];        // 16 KB
    __shared__ float2 sY[4 * 64];         // [j][k0], 2 KB

    int tid = threadIdx.x;
    int d   = blockIdx.x >> 4;
    int m0b = (blockIdx.x & 15) << 2;

    if (blockIdx.x < 32) {                // table side-job (no dependency)
        int t = blockIdx.x * 256 + tid;   // (n,d) pair index < 8192
        float w  = softplus_f(W[t]);
        float tv = tau[t];
        float rv = fract_f(tv * ((float)M_STRIDE / (float)M_COLS));  // tv/4
        float4 t4;
        t4.x = cos_rev(rv);               // step = e^{+i 2pi tau*1024/M}
        t4.y = sin_rev(rv);
        float rc = fract_f(-tv);          // e^{-2pi i tau}
        t4.z = w * cos_rev(rc);           // wcr
        t4.w = w * sin_rev(rc);           // wci
        g_Tab4[t] = t4;
        g_Tab2[t] = make_float2(w, tv);
    }

    const float4* Hrow4 = (const float4*)(H + d * M_COLS);
    #pragma unroll
    for (int p = 0; p < 4; ++p) {
        int i = p * 256 + tid;            // 1024 float4 per row
        float4 h4 = Hrow4[i];
        sHs[i*4+0] = softplus_f(h4.x);
        sHs[i*4+1] = softplus_f(h4.y);
        sHs[i*4+2] = softplus_f(h4.z);
        sHs[i*4+3] = softplus_f(h4.w);
    }
    __syncthreads();

    {   // stage A
        int k0 = tid & 63, j = tid >> 6;
        int m0 = m0b + j;
        float mrev = (float)m0 * (1.0f / 64.0f);
        float rr =  cos_rev(mrev);
        float ri = -sin_rev(mrev);        // step = e^{-2pi i m0/64}
        float twr = 1.0f, twi = 0.0f;
        float ar = 0.0f, ai = 0.0f;
        #pragma unroll
        for (int k1 = 0; k1 < 64; ++k1) {
            float v = sHs[(k1 << 6) + k0];
            ar = fmaf(v, twr, ar);
            ai = fmaf(v, twi, ai);
            float nr = fmaf(twr, rr, -(twi * ri));
            twi      = fmaf(twr, ri,   twi * rr);
            twr = nr;
        }
        sY[(j << 6) + k0] = make_float2(ar, ai);
    }
    __syncthreads();

    {   // stage B
        int m1 = tid & 63, j = tid >> 6;
        int m  = (m1 << 6) + m0b + j;
        float mrev = (float)m * (1.0f / 4096.0f);
        float rr =  cos_rev(mrev);
        float ri = -sin_rev(mrev);        // step = e^{-2pi i m/4096}
        float twr = 1.0f, twi = 0.0f;
        float ar = 0.0f, ai = 0.0f;
        #pragma unroll
        for (int k0 = 0; k0 < 64; ++k0) {
            float2 y = sY[(j << 6) + k0];
            ar = fmaf(y.x, twr, fmaf(-y.y, twi, ar));
            ai = fmaf(y.x, twi, fmaf( y.y, twr, ai));
            float nr = fmaf(twr, rr, -(twi * ri));
            twi      = fmaf(twr, ri,   twi * rr);
            twr = nr;
        }
        g_Hft[d * M_COLS + m] = make_float2(ar, ai);
    }
}

// ---------------------------------------------------------------------------
// Main (UNCHANGED from R13). Pure function of g_Hft/g_Tab -> out; idempotent,
// so launching it multiple times is correct and graph-safe. This round runs
// it 3x to measure its true duration: main = (total - 19.2)/2.
// ---------------------------------------------------------------------------
__global__ void shiftnmf_main(float* __restrict__ out) {
    int tid = threadIdx.x;
    int m0  = blockIdx.x * 256 + tid;     // 0..1023 ; m_j = 1 + m0 + j*1024
    int n0  = blockIdx.y * R_ROWS;

    float fm0 = (float)(1 + m0) * (1.0f / (float)M_COLS);

    float accm[R_ROWS][T_PTS];            // direct outputs, m
    float accx[R_ROWS][T_PTS];            // mirror outputs, 4096-m
    #pragma unroll
    for (int r = 0; r < R_ROWS; ++r)
        #pragma unroll
        for (int j = 0; j < T_PTS; ++j) { accm[r][j] = 0.0f; accx[r][j] = 0.0f; }

    #pragma unroll
    for (int d = 0; d < RANK; ++d) {
        float ur[R_ROWS], ui[R_ROWS];                 // unit phasor (per-lane)
        float vr[R_ROWS], vi[R_ROWS];                 // step (SGPR)
        float ws[R_ROWS], wcr[R_ROWS], wci[R_ROWS];   // weights (SGPR)
        #pragma unroll
        for (int r = 0; r < R_ROWS; ++r) {
            int nd = (n0 + r) * RANK + d;
            float4 t4 = g_Tab4[nd];                   // block-uniform
            float2 t2 = g_Tab2[nd];
            vr[r]  = rfl(t4.x);  vi[r]  = rfl(t4.y);
            wcr[r] = rfl(t4.z);  wci[r] = rfl(t4.w);
            ws[r]  = rfl(t2.x);
            float tv = rfl(t2.y);
            float r0 = fract_f(tv * fm0);             // only per-thread trig
            ur[r] = cos_rev(r0);                      // u = e^{+i 2pi tau m_0/M}
            ui[r] = sin_rev(r0);
        }

        const float2* hp = g_Hft + d * M_COLS + 1 + m0;
        #pragma unroll
        for (int j = 0; j < T_PTS; ++j) {
            float2 h = hp[j * M_STRIDE];              // coalesced, L2-resident
            #pragma unroll
            for (int r = 0; r < R_ROWS; ++r) {
                float t1 = ui[r] * h.y;
                float zr = fmaf(ur[r], h.x, t1);      // Re(conj(u)h)
                float t2v = ui[r] * h.x;
                float zi = fmaf(ur[r], h.y, -t2v);    // Im(conj(u)h)
                accm[r][j] = fmaf(ws[r],  zr, accm[r][j]);
                accx[r][j] = fmaf(wcr[r], zr, fmaf(wci[r], zi, accx[r][j]));
                if (j < T_PTS - 1) {                  // u *= v (skip dead last)
                    float nr = fmaf(ur[r], vr[r], -(ui[r] * vi[r]));
                    ui[r]    = fmaf(ur[r], vi[r],   ui[r] * vr[r]);
                    ur[r]    = nr;
                }
            }
        }
    }

    #pragma unroll
    for (int r = 0; r < R_ROWS; ++r) {
        float* op = out + (n0 + r) * M_COLS;
        #pragma unroll
        for (int j = 0; j < T_PTS; ++j)
            op[1 + m0 + j * M_STRIDE] = accm[r][j];    // m in [1,2048]
        #pragma unroll
        for (int j = 0; j < T_PTS; ++j)
            op[4095 - m0 - j * M_STRIDE] = accx[r][j]; // 4096-m in [2048,4095]
    }

    if (blockIdx.x == 0 && tid == 0) {                // column 0, direct
        #pragma unroll
        for (int r = 0; r < R_ROWS; ++r) {
            int n = n0 + r;
            float a = 0.0f;
            #pragma unroll
            for (int d = 0; d < RANK; ++d)
                a = fmaf(g_Tab2[n * RANK + d].x, g_Hft[d * M_COLS].x, a);
            out[n * M_COLS] = a;
        }
    }
}

extern "C" void kernel_launch(void* const* d_in, const int* in_sizes, int n_in,
                              void* d_out, int out_size, void* d_ws, size_t ws_size,
                              hipStream_t stream) {
    const float* W   = (const float*)d_in[0];   // [1024, 8]
    const float* H   = (const float*)d_in[1];   // [8, 4096]
    const float* tau = (const float*)d_in[2];   // [1024, 8]

    fft_fused<<<dim3(RANK * 16), dim3(256), 0, stream>>>(H, W, tau);

    dim3 grid(M_COLS / 2 / (256 * T_PTS), N_ROWS / R_ROWS);  // (4, 512)
    // CALIBRATION: main is idempotent; run 3x. main_dur = (total - 19.2)/2.
    shiftnmf_main<<<grid, dim3(256), 0, stream>>>((float*)d_out);
    shiftnmf_main<<<grid, dim3(256), 0, stream>>>((float*)d_out);
    shiftnmf_main<<<grid, dim3(256), 0, stream>>>((float*)d_out);
}

// Round 15
// 29.089 us; speedup vs baseline: 1.2387x; 1.2387x over previous
//
#include <hip/hip_runtime.h>
#include <math.h>

#define N_ROWS 1024
#define RANK   8
#define M_COLS 4096

#define R_ROWS   2      // n-rows per thread
#define T_PTS    2      // direct points per thread in [1,2048], stride 1024
#define M_STRIDE 1024

// Static device scratch (fully overwritten every call before read).
__device__ float2 g_Hft[RANK * M_COLS];        // FFT of softplus(H), 256 KB
__device__ float4 g_Tab4[N_ROWS * RANK];       // {vr, vi, wcr, wci}, 128 KB
__device__ float2 g_Tab2[N_ROWS * RANK];       // {ws, tau}, 64 KB
__device__ float2 g_T1[N_ROWS * RANK * 64];    // e^{2pi i tau l/4096}, l<64, 4 MB
__device__ float2 g_T2[N_ROWS * RANK * 16];    // e^{2pi i tau (64q+1)/4096}, 1 MB

// fast softplus: 2 trans + ~4 VALU. exact for x>20; inputs are ~N(0,1).
__device__ __forceinline__ float softplus_f(float x) {
    float t = __expf(x);
    float r = 0.69314718056f * __log2f(1.0f + t);
    return (x > 20.0f) ? x : r;
}
// hw trig: v_sin/v_cos compute sin/cos(2*pi*x), x in revolutions.
__device__ __forceinline__ float sin_rev(float x) { return __builtin_amdgcn_sinf(x); }
__device__ __forceinline__ float cos_rev(float x) { return __builtin_amdgcn_cosf(x); }
__device__ __forceinline__ float fract_f(float x) { return __builtin_amdgcn_fractf(x); }
// block-uniform float -> SGPR
__device__ __forceinline__ float rfl(float x) {
    return __int_as_float(__builtin_amdgcn_readfirstlane(__float_as_int(x)));
}

// ---------------------------------------------------------------------------
// Fused FFT + ALL table generation.
// Blocks 0..127: softplus(H) + 64x64 DFT -> g_Hft (R13-proven, unchanged);
//                blocks 0..31 also fill g_Tab4/g_Tab2 (side-job).
// Blocks 128..2175:  g_T1 (524288 entries, 1/thread) — phasor lane table.
// Blocks 2176..2687: g_T2 (131072 entries, 1/thread) — phasor q table.
// Table blocks return BEFORE any __syncthreads (uniform per block). They run
// on CUs the 128 fft blocks leave idle -> ~zero added wall time.
// ---------------------------------------------------------------------------
__global__ void fft_fused(const float* __restrict__ H,
                          const float* __restrict__ W,
                          const float* __restrict__ tau) {
    int tid = threadIdx.x;

    if (blockIdx.x >= 128) {
        int b = blockIdx.x - 128;
        if (b < 2048) {                   // g_T1: idx = nd*64 + l
            int idx = b * 256 + tid;
            int nd  = idx >> 6;
            int l   = idx & 63;
            float tv  = tau[nd];
            float rev = fract_f(tv * ((float)l * (1.0f / (float)M_COLS)));
            g_T1[idx] = make_float2(cos_rev(rev), sin_rev(rev));
        } else {                          // g_T2: idx = nd*16 + q
            int idx = (b - 2048) * 256 + tid;
            int nd  = idx >> 4;
            int q   = idx & 15;
            float tv  = tau[nd];
            float rev = fract_f(tv * ((float)(64 * q + 1) * (1.0f / (float)M_COLS)));
            g_T2[idx] = make_float2(cos_rev(rev), sin_rev(rev));
        }
        return;
    }

    __shared__ float  sHs[M_COLS];        // 16 KB
    __shared__ float2 sY[4 * 64];         // [j][k0], 2 KB

    int d   = blockIdx.x >> 4;
    int m0b = (blockIdx.x & 15) << 2;

    if (blockIdx.x < 32) {                // Tab4/Tab2 side-job (no dependency)
        int t = blockIdx.x * 256 + tid;   // (n,d) pair index < 8192
        float w  = softplus_f(W[t]);
        float tv = tau[t];
        float rv = fract_f(tv * ((float)M_STRIDE / (float)M_COLS));  // tv/4
        float4 t4;
        t4.x = cos_rev(rv);               // step = e^{+i 2pi tau*1024/M}
        t4.y = sin_rev(rv);
        float rc = fract_f(-tv);          // e^{-2pi i tau}
        t4.z = w * cos_rev(rc);           // wcr
        t4.w = w * sin_rev(rc);           // wci
        g_Tab4[t] = t4;
        g_Tab2[t] = make_float2(w, tv);
    }

    const float4* Hrow4 = (const float4*)(H + d * M_COLS);
    #pragma unroll
    for (int p = 0; p < 4; ++p) {
        int i = p * 256 + tid;            // 1024 float4 per row
        float4 h4 = Hrow4[i];
        sHs[i*4+0] = softplus_f(h4.x);
        sHs[i*4+1] = softplus_f(h4.y);
        sHs[i*4+2] = softplus_f(h4.z);
        sHs[i*4+3] = softplus_f(h4.w);
    }
    __syncthreads();

    {   // stage A
        int k0 = tid & 63, j = tid >> 6;
        int m0 = m0b + j;
        float mrev = (float)m0 * (1.0f / 64.0f);
        float rr =  cos_rev(mrev);
        float ri = -sin_rev(mrev);        // step = e^{-2pi i m0/64}
        float twr = 1.0f, twi = 0.0f;
        float ar = 0.0f, ai = 0.0f;
        #pragma unroll
        for (int k1 = 0; k1 < 64; ++k1) {
            float v = sHs[(k1 << 6) + k0];
            ar = fmaf(v, twr, ar);
            ai = fmaf(v, twi, ai);
            float nr = fmaf(twr, rr, -(twi * ri));
            twi      = fmaf(twr, ri,   twi * rr);
            twr = nr;
        }
        sY[(j << 6) + k0] = make_float2(ar, ai);
    }
    __syncthreads();

    {   // stage B
        int m1 = tid & 63, j = tid >> 6;
        int m  = (m1 << 6) + m0b + j;
        float mrev = (float)m * (1.0f / 4096.0f);
        float rr =  cos_rev(mrev);
        float ri = -sin_rev(mrev);        // step = e^{-2pi i m/4096}
        float twr = 1.0f, twi = 0.0f;
        float ar = 0.0f, ai = 0.0f;
        #pragma unroll
        for (int k0 = 0; k0 < 64; ++k0) {
            float2 y = sY[(j << 6) + k0];
            ar = fmaf(y.x, twr, fmaf(-y.y, twi, ar));
            ai = fmaf(y.x, twi, fmaf( y.y, twr, ai));
            float nr = fmaf(twr, rr, -(twi * ri));
            twi      = fmaf(twr, ri,   twi * rr);
            twr = nr;
        }
        g_Hft[d * M_COLS + m] = make_float2(ar, ai);
    }
}

// ---------------------------------------------------------------------------
// Main: ZERO transcendental ops. Hermitian mirroring (R12-validated math).
// For m = 1+m0+j*1024, m0 = 64q+l:
//   u = T2[nd,q] * T1[nd,l]   (4 VALU complex mul; T1 coalesced by lane,
//                              T2/v/weights wave-uniform -> SGPR via rfl)
//   zr = ur*hr + ui*hi ; zi = ur*hi - ui*hr
//   Re V[n,m]      += ws * zr
//   Re V[n,4096-m] += wcr*zr + wci*zi
// grid (4,512) = 2048 blocks = 8 waves/SIMD; ~45 live VGPRs.
// ---------------------------------------------------------------------------
__global__ void shiftnmf_main(float* __restrict__ out) {
    int tid = threadIdx.x;
    int m0  = blockIdx.x * 256 + tid;     // 0..1023 ; m_j = 1 + m0 + j*1024
    int n0  = blockIdx.y * R_ROWS;
    int l   = tid & 63;                   // = m0 & 63
    int q   = (m0 >> 6) & 15;             // wave-uniform

    float accm[R_ROWS][T_PTS];            // direct outputs, m
    float accx[R_ROWS][T_PTS];            // mirror outputs, 4096-m
    #pragma unroll
    for (int r = 0; r < R_ROWS; ++r)
        #pragma unroll
        for (int j = 0; j < T_PTS; ++j) { accm[r][j] = 0.0f; accx[r][j] = 0.0f; }

    #pragma unroll
    for (int d = 0; d < RANK; ++d) {
        float ur[R_ROWS], ui[R_ROWS];                 // unit phasor (per-lane)
        float vr[R_ROWS], vi[R_ROWS];                 // step (SGPR)
        float ws[R_ROWS], wcr[R_ROWS], wci[R_ROWS];   // weights (SGPR)
        #pragma unroll
        for (int r = 0; r < R_ROWS; ++r) {
            int nd = (n0 + r) * RANK + d;
            float4 t4 = g_Tab4[nd];                   // block-uniform
            vr[r]  = rfl(t4.x);  vi[r]  = rfl(t4.y);
            wcr[r] = rfl(t4.z);  wci[r] = rfl(t4.w);
            ws[r]  = rfl(g_Tab2[nd].x);
            float2 t2 = g_T2[nd * 16 + q];            // wave-uniform
            float t2r = rfl(t2.x), t2i = rfl(t2.y);
            float2 t1 = g_T1[nd * 64 + l];            // coalesced 8B/lane
            ur[r] = fmaf(t1.x, t2r, -(t1.y * t2i));   // u = T1*T2
            ui[r] = fmaf(t1.x, t2i,   t1.y * t2r);
        }

        const float2* hp = g_Hft + d * M_COLS + 1 + m0;
        #pragma unroll
        for (int j = 0; j < T_PTS; ++j) {
            float2 h = hp[j * M_STRIDE];              // coalesced, L2-resident
            #pragma unroll
            for (int r = 0; r < R_ROWS; ++r) {
                float t1v = ui[r] * h.y;
                float zr = fmaf(ur[r], h.x, t1v);     // Re(conj(u)h)
                float t2v = ui[r] * h.x;
                float zi = fmaf(ur[r], h.y, -t2v);    // Im(conj(u)h)
                accm[r][j] = fmaf(ws[r],  zr, accm[r][j]);
                accx[r][j] = fmaf(wcr[r], zr, fmaf(wci[r], zi, accx[r][j]));
                if (j < T_PTS - 1) {                  // u *= v (skip dead last)
                    float nr = fmaf(ur[r], vr[r], -(ui[r] * vi[r]));
                    ui[r]    = fmaf(ur[r], vi[r],   ui[r] * vr[r]);
                    ur[r]    = nr;
                }
            }
        }
    }

    #pragma unroll
    for (int r = 0; r < R_ROWS; ++r) {
        float* op = out + (n0 + r) * M_COLS;
        #pragma unroll
        for (int j = 0; j < T_PTS; ++j)
            op[1 + m0 + j * M_STRIDE] = accm[r][j];    // m in [1,2048]
        #pragma unroll
        for (int j = 0; j < T_PTS; ++j)
            op[4095 - m0 - j * M_STRIDE] = accx[r][j]; // 4096-m in [2048,4095]
    }

    if (blockIdx.x == 0 && tid == 0) {                // column 0, direct
        #pragma unroll
        for (int r = 0; r < R_ROWS; ++r) {
            int n = n0 + r;
            float a = 0.0f;
            #pragma unroll
            for (int d = 0; d < RANK; ++d)
                a = fmaf(g_Tab2[n * RANK + d].x, g_Hft[d * M_COLS].x, a);
            out[n * M_COLS] = a;
        }
    }
}

extern "C" void kernel_launch(void* const* d_in, const int* in_sizes, int n_in,
                              void* d_out, int out_size, void* d_ws, size_t ws_size,
                              hipStream_t stream) {
    const float* W   = (const float*)d_in[0];   // [1024, 8]
    const float* H   = (const float*)d_in[1];   // [8, 4096]
    const float* tau = (const float*)d_in[2];   // [1024, 8]

    // 128 fft blocks + 2048 T1-table blocks + 512 T2-table blocks
    fft_fused<<<dim3(128 + 2048 + 512), dim3(256), 0, stream>>>(H, W, tau);

    dim3 grid(M_COLS / 2 / (256 * T_PTS), N_ROWS / R_ROWS);  // (4, 512)
    shiftnmf_main<<<grid, dim3(256), 0, stream>>>((float*)d_out);
}